// Round 2
// baseline (241.086 us; speedup 1.0000x reference)
//
#include <hip/hip_runtime.h>
#include <math.h>

// Problem constants
#define B_N   4
#define CIN   21
#define HIDC  48
#define H0    81
#define NP    6561      // 81*81
#define HH    324
#define NPH   104976    // 324*324

__device__ __forceinline__ float tanh_fast(float x) {
    // tanh(x) = 1 - 2/(exp(2x)+1); exact limits at +-inf
    float e = __expf(2.f * x);
    return 1.f - 2.f / (e + 1.f);
}

__device__ __forceinline__ float sel8(const float v[8], int s) {
    float r = v[0];
    #pragma unroll
    for (int i = 1; i < 8; ++i) r = (s == i) ? v[i] : r;
    return r;
}
__device__ __forceinline__ float sel9(const float v[9], int s) {
    float r = v[0];
    #pragma unroll
    for (int i = 1; i < 9; ++i) r = (s == i) ? v[i] : r;
    return r;
}

// ---------------------------------------------------------------------------
// K1: conv1 for BOTH heads (21 -> 48, relu). 96 total output channels split
// into 6 groups of 16. Block = 256 threads = 16x16 pixel tile; x tile staged
// in LDS. Weight reads are wave-uniform (scalar cache).
// ---------------------------------------------------------------------------
__global__ __launch_bounds__(256) void k1_conv1(
    const float* __restrict__ x,
    const float* __restrict__ w1o, const float* __restrict__ b1o,
    const float* __restrict__ w1g, const float* __restrict__ b1g,
    float* __restrict__ hid_o, float* __restrict__ hid_g)
{
    __shared__ float xs[CIN][18][18];
    const int tile = blockIdx.x;        // 0..35
    const int ocg  = blockIdx.y;        // 0..5
    const int b    = blockIdx.z;
    const int ty0 = (tile / 6) * 16, tx0 = (tile % 6) * 16;
    const int tid = threadIdx.x;
    const float* xb = x + (size_t)b * CIN * NP;
    for (int e = tid; e < CIN * 18 * 18; e += 256) {
        int ic = e / 324, r = e % 324, yy = r / 18, xx = r % 18;
        int gy = ty0 - 1 + yy, gx = tx0 - 1 + xx;
        float v = 0.f;
        if (gy >= 0 && gy < H0 && gx >= 0 && gx < H0) v = xb[ic * NP + gy * H0 + gx];
        xs[ic][yy][xx] = v;
    }
    __syncthreads();
    const int py = tid >> 4, px = tid & 15;
    const int oy = ty0 + py, ox = tx0 + px;
    const bool head_o = (ocg < 3);
    const float* w  = head_o ? w1o : w1g;
    const float* bb = head_o ? b1o : b1g;
    float* out      = head_o ? hid_o : hid_g;
    const int oc0 = (head_o ? ocg : ocg - 3) * 16;
    float acc[16];
    #pragma unroll
    for (int o = 0; o < 16; o++) acc[o] = bb[oc0 + o];
    for (int ic = 0; ic < CIN; ic++) {
        #pragma unroll
        for (int ky = 0; ky < 3; ky++) {
            #pragma unroll
            for (int kx = 0; kx < 3; kx++) {
                const float xv = xs[ic][py + ky][px + kx];
                const float* wp = w + (oc0 * CIN + ic) * 9 + ky * 3 + kx;
                #pragma unroll
                for (int o = 0; o < 16; o++)
                    acc[o] = fmaf(xv, wp[o * (CIN * 9)], acc[o]);
            }
        }
    }
    if (oy < H0 && ox < H0) {
        float* op = out + ((size_t)b * HIDC + oc0) * NP + oy * H0 + ox;
        #pragma unroll
        for (int o = 0; o < 16; o++) op[o * NP] = fmaxf(acc[o], 0.f);
    }
}

// ---------------------------------------------------------------------------
// K2 v2: conv2 + mask math, slice-parallel. 256 threads = 4 waves; each wave
// handles 8 pixels x 8 channel-slices (6 ch each). Butterfly shfl_xor over
// lanes {8,16,32} sums the 48-channel reduction; all 8 redundant lanes then
// compute the epilogue (no divergence) and split the 27 stores by slice.
// Weights staged in LDS transposed to [ic][tap][d0..7] -> 2x ds_read_b128.
// ---------------------------------------------------------------------------
__global__ __launch_bounds__(256) void k2_conv2_masks(
    const float* __restrict__ hid_o, const float* __restrict__ hid_g,
    const float* __restrict__ w2o, const float* __restrict__ b2o,
    const float* __restrict__ w2g, const float* __restrict__ b2g,
    float* __restrict__ v_out,
    float* __restrict__ g_buf, float* __restrict__ m_lp, float* __restrict__ m_hp)
{
    __shared__ float wsm[HIDC * 9 * 8];   // [ic*9+tap][d]
    __shared__ float wgm[HIDC * 9];
    const int tid = threadIdx.x;
    for (int i = tid; i < HIDC * 9 * 8; i += 256) {
        int d = i / (HIDC * 9), r = i - d * (HIDC * 9);
        wsm[r * 8 + d] = w2o[i];
    }
    for (int i = tid; i < HIDC * 9; i += 256) wgm[i] = w2g[i];
    __syncthreads();

    const int b    = blockIdx.y;
    const int lane = tid & 63;
    const int wv   = tid >> 6;
    const int s    = lane >> 3;                 // channel slice 0..7
    const int p    = blockIdx.x * 32 + wv * 8 + (lane & 7);
    const bool valid = (p < NP);
    const int oy = p / H0, ox = p - oy * H0;

    const int ic0 = s * 6;
    const float* po_b = hid_o + ((size_t)b * HIDC + ic0) * NP;
    const float* pg_b = hid_g + ((size_t)b * HIDC + ic0) * NP;

    float a0 = 0.f, a1 = 0.f, a2 = 0.f, a3 = 0.f;
    float a4 = 0.f, a5 = 0.f, a6 = 0.f, a7 = 0.f, ag = 0.f;
    #pragma unroll
    for (int ky = 0; ky < 3; ky++) {
        const int iy = oy + ky - 1;
        const bool rok = ((unsigned)iy < (unsigned)H0);
        #pragma unroll
        for (int kx = 0; kx < 3; kx++) {
            const int ix = ox + kx - 1;
            const bool ok = valid && rok && ((unsigned)ix < (unsigned)H0);
            const int off = iy * H0 + ix;
            const int tap = ky * 3 + kx;
            #pragma unroll
            for (int j = 0; j < 6; ++j) {
                const float vo = ok ? po_b[j * NP + off] : 0.f;
                const float vg = ok ? pg_b[j * NP + off] : 0.f;
                const float* wp = &wsm[((ic0 + j) * 9 + tap) * 8];
                a0 = fmaf(vo, wp[0], a0);
                a1 = fmaf(vo, wp[1], a1);
                a2 = fmaf(vo, wp[2], a2);
                a3 = fmaf(vo, wp[3], a3);
                a4 = fmaf(vo, wp[4], a4);
                a5 = fmaf(vo, wp[5], a5);
                a6 = fmaf(vo, wp[6], a6);
                a7 = fmaf(vo, wp[7], a7);
                ag = fmaf(vg, wgm[(ic0 + j) * 9 + tap], ag);
            }
        }
    }
    // butterfly reduce across the 8 slices (xor lane bits 3,4,5)
    #pragma unroll
    for (int o = 8; o < 64; o <<= 1) {
        a0 += __shfl_xor(a0, o); a1 += __shfl_xor(a1, o);
        a2 += __shfl_xor(a2, o); a3 += __shfl_xor(a3, o);
        a4 += __shfl_xor(a4, o); a5 += __shfl_xor(a5, o);
        a6 += __shfl_xor(a6, o); a7 += __shfl_xor(a7, o);
        ag += __shfl_xor(ag, o);
    }
    if (!valid) return;

    float v[8];
    v[0] = tanh_fast(a0 + b2o[0]); v[1] = tanh_fast(a1 + b2o[1]);
    v[2] = tanh_fast(a2 + b2o[2]); v[3] = tanh_fast(a3 + b2o[3]);
    v[4] = tanh_fast(a4 + b2o[4]); v[5] = tanh_fast(a5 + b2o[5]);
    v[6] = tanh_fast(a6 + b2o[6]); v[7] = tanh_fast(a7 + b2o[7]);
    const float g = 1.f / (1.f + __expf(-(ag + b2g[0])));

    // ker[n] = -(1/8) * sum_d v[d]*DT[d][n]; center (+2.5) at n=4
    constexpr float DT[8][9] = {
        {-1, 0, 1, -1, 0, 1, -1, 0, 1},
        {-1,-1, 0, -1, 0, 1,  0, 1, 1},
        {-1,-1,-1,  0, 0, 0,  1, 1, 1},
        { 0,-1,-1,  1, 0,-1,  1, 1, 0},
        { 1, 0,-1,  1, 0,-1,  1, 0,-1},
        { 1, 1, 0,  1, 0,-1,  0,-1,-1},
        { 1, 1, 1,  0, 0, 0, -1,-1,-1},
        { 0, 1, 1, -1, 0, 1, -1,-1, 0}};
    float ker[9];
    #pragma unroll
    for (int n = 0; n < 9; n++) {
        float t = 0.f;
        #pragma unroll
        for (int d = 0; d < 8; d++) t += v[d] * DT[d][n];
        ker[n] = -0.125f * t;
    }
    ker[4] += 2.5f;
    float mx = ker[0];
    #pragma unroll
    for (int n = 1; n < 9; n++) mx = fmaxf(mx, ker[n]);
    float ex[9], sum = 0.f;
    #pragma unroll
    for (int n = 0; n < 9; n++) { ex[n] = __expf((ker[n] - mx) * 2.0f); sum += ex[n]; }
    const float rs = 1.f / sum;
    float sm[9];
    #pragma unroll
    for (int n = 0; n < 9; n++) sm[n] = ex[n] * rs;
    float mean = 0.f;
    #pragma unroll
    for (int n = 0; n < 9; n++) mean += ker[n];
    mean *= (1.f / 9.f);
    float den = 1e-8f;
    #pragma unroll
    for (int n = 0; n < 9; n++) den += fabsf(ker[n] - mean);
    const float rd = 1.f / den;
    float hp[9];
    #pragma unroll
    for (int n = 0; n < 9; n++) hp[n] = (ker[n] - mean) * rd;

    // distributed stores: slice s writes channel-plane s (coalesced per group)
    v_out[((size_t)b * 8 + s) * NP + p] = sel8(v, s);
    m_lp[((size_t)b * 9 + s) * NP + p] = sel9(sm, s);
    m_hp[((size_t)b * 9 + s) * NP + p] = sel9(hp, s);
    if (s == 0) {
        g_buf[(size_t)b * NP + p] = g;
        m_lp[((size_t)b * 9 + 8) * NP + p] = sm[8];
        m_hp[((size_t)b * 9 + 8) * NP + p] = hp[8];
    }
}

// ---------------------------------------------------------------------------
// K3 v2: low-res 9-tap aggregation (reflect pad), thread = (b, c, pixel).
// ---------------------------------------------------------------------------
__global__ __launch_bounds__(256) void k3_agg(
    const float* __restrict__ x, const float* __restrict__ m_lp,
    const float* __restrict__ m_hp,
    float* __restrict__ a_lp, float* __restrict__ a_hp)
{
    const int pix = blockIdx.x * 256 + threadIdx.x;
    if (pix >= NP) return;
    const int c = blockIdx.y, b = blockIdx.z;
    const int oy = pix / H0, ox = pix - oy * H0;
    float ml[9], mh[9];
    const float* mlb = m_lp + (size_t)b * 9 * NP + pix;
    const float* mhb = m_hp + (size_t)b * 9 * NP + pix;
    #pragma unroll
    for (int n = 0; n < 9; n++) { ml[n] = mlb[n * NP]; mh[n] = mhb[n * NP]; }
    const float* xc = x + ((size_t)b * CIN + c) * NP;
    float alp = 0.f, ahp = 0.f;
    #pragma unroll
    for (int ky = 0; ky < 3; ky++) {
        int iy = oy + ky - 1;
        iy = iy < 0 ? -iy : (iy > H0 - 1 ? 2 * (H0 - 1) - iy : iy);
        #pragma unroll
        for (int kx = 0; kx < 3; kx++) {
            int ix = ox + kx - 1;
            ix = ix < 0 ? -ix : (ix > H0 - 1 ? 2 * (H0 - 1) - ix : ix);
            const float p = xc[iy * H0 + ix];
            const int n = ky * 3 + kx;
            alp = fmaf(p, ml[n], alp);
            ahp = fmaf(p, mh[n], ahp);
        }
    }
    a_lp[((size_t)b * CIN + c) * NP + pix] = alp;
    a_hp[((size_t)b * CIN + c) * NP + pix] = ahp;
}

// ---------------------------------------------------------------------------
// K4: hi-res blend. One thread = one float4 of an output row. The repeat
// index W>>2 is constant within the float4 so agg/g/lam are scalars; only
// bilinear x_up varies. blockIdx.y==CIN writes g_up.
// ---------------------------------------------------------------------------
__global__ __launch_bounds__(256) void k4_up(
    const float* __restrict__ x, const float* __restrict__ g_buf,
    const float* __restrict__ a_lp, const float* __restrict__ a_hp,
    const float* __restrict__ beta,
    float* __restrict__ y_out, float* __restrict__ gup_out)
{
    const int tid = threadIdx.x;
    if (tid >= 243) return;
    const int c = blockIdx.y;              // 0..20 = channel, 21 = g_up
    const int b = blockIdx.z;
    const int H = blockIdx.x * 3 + tid / 81;
    const int wq = tid % 81;
    const int h0r = H >> 2;
    const float g = g_buf[(size_t)b * NP + h0r * H0 + wq];
    if (c == CIN) {
        *reinterpret_cast<float4*>(gup_out + (size_t)b * NPH + H * HH + wq * 4) =
            make_float4(g, g, g, g);
        return;
    }
    const float tb = tanh_fast(beta[0]);
    const float alp = a_lp[((size_t)b * CIN + c) * NP + h0r * H0 + wq];
    const float ahp = a_hp[((size_t)b * CIN + c) * NP + h0r * H0 + wq];
    const float lam = 0.15f * (1.f - g);
    const float gh = tb * g;
    const float* xc = x + ((size_t)b * CIN + c) * NP;
    const float ysf = (float)H * (80.f / 323.f);
    int y0 = (int)ysf;
    if (y0 > H0 - 2) y0 = H0 - 2;
    const float wy = ysf - (float)y0;
    const float* r0 = xc + y0 * H0;
    const float* r1 = r0 + H0;
    float res[4];
    #pragma unroll
    for (int i = 0; i < 4; i++) {
        const int W = wq * 4 + i;
        const float xsf = (float)W * (80.f / 323.f);
        int x0 = (int)xsf;
        if (x0 > H0 - 2) x0 = H0 - 2;
        const float wx = xsf - (float)x0;
        const float x00 = r0[x0], x01 = r0[x0 + 1];
        const float x10 = r1[x0], x11 = r1[x0 + 1];
        const float top = x00 + (x01 - x00) * wx;
        const float bot = x10 + (x11 - x10) * wx;
        const float xup = top + (bot - top) * wy;
        res[i] = xup + lam * (alp - xup) + gh * ahp;
    }
    *reinterpret_cast<float4*>(y_out + ((size_t)b * CIN + c) * NPH + H * HH + wq * 4) =
        make_float4(res[0], res[1], res[2], res[3]);
}

// ---------------------------------------------------------------------------
extern "C" void kernel_launch(void* const* d_in, const int* in_sizes, int n_in,
                              void* d_out, int out_size, void* d_ws, size_t ws_size,
                              hipStream_t stream)
{
    const float* x    = (const float*)d_in[0];
    const float* w1o  = (const float*)d_in[1];
    const float* b1o  = (const float*)d_in[2];
    const float* w2o  = (const float*)d_in[3];
    const float* b2o  = (const float*)d_in[4];
    const float* w1g  = (const float*)d_in[5];
    const float* b1g  = (const float*)d_in[6];
    const float* w2g  = (const float*)d_in[7];
    const float* b2g  = (const float*)d_in[8];
    const float* beta = (const float*)d_in[9];
    float* out = (float*)d_out;
    float* wsf = (float*)d_ws;

    float* hid_o = wsf;
    float* hid_g = hid_o + (size_t)B_N * HIDC * NP;
    float* m_lp  = hid_g + (size_t)B_N * HIDC * NP;
    float* m_hp  = m_lp + (size_t)B_N * 9 * NP;
    float* g_buf = m_hp + (size_t)B_N * 9 * NP;
    float* a_lp  = g_buf + (size_t)B_N * NP;
    float* a_hp  = a_lp + (size_t)B_N * CIN * NP;

    // output layout: y [4,21,324,324], v [4,8,81,81], g_up [4,1,324,324]
    float* y_out = out;
    float* v_out = out + (size_t)B_N * CIN * NPH;
    float* gup   = v_out + (size_t)B_N * 8 * NP;

    k1_conv1<<<dim3(36, 6, B_N), 256, 0, stream>>>(x, w1o, b1o, w1g, b1g, hid_o, hid_g);
    k2_conv2_masks<<<dim3((NP + 31) / 32, B_N), 256, 0, stream>>>(
        hid_o, hid_g, w2o, b2o, w2g, b2g, v_out, g_buf, m_lp, m_hp);
    k3_agg<<<dim3((NP + 255) / 256, CIN, B_N), 256, 0, stream>>>(x, m_lp, m_hp, a_lp, a_hp);
    k4_up<<<dim3(108, CIN + 1, B_N), 256, 0, stream>>>(x, g_buf, a_lp, a_hp, beta, y_out, gup);
}

// Round 3
// 222.861 us; speedup vs baseline: 1.0818x; 1.0818x over previous
//
#include <hip/hip_runtime.h>
#include <math.h>

// Problem constants
#define B_N   4
#define CIN   21
#define HIDC  48
#define H0    81
#define NP    6561      // 81*81
#define HH    324
#define NPH   104976    // 324*324

__device__ __forceinline__ float tanh_fast(float x) {
    float e = __expf(2.f * x);
    return 1.f - 2.f / (e + 1.f);
}

// ---------------------------------------------------------------------------
// K1 v3: conv1 both heads (21 -> 96 = 48 o + 48 g), relu.
// Block: 16x16 pixel tile x 32 oc. Thread: 4 px x 8 oc. Weights transposed
// into LDS [ic*9+tap][oc32]; x tile row-padded to 20 for aligned b128 reads.
// ---------------------------------------------------------------------------
__global__ __launch_bounds__(256) void k1_conv1(
    const float* __restrict__ x,
    const float* __restrict__ w1o, const float* __restrict__ b1o,
    const float* __restrict__ w1g, const float* __restrict__ b1g,
    float* __restrict__ hid_o, float* __restrict__ hid_g)
{
    __shared__ __align__(16) float xs[CIN * 18 * 20];   // [ic][yy][xx(pad 20)]
    __shared__ __align__(16) float wt[189 * 32];        // [(ic*9+tap)*32 + oc]
    __shared__ float bs[32];
    const int tid = threadIdx.x;
    const int tile = blockIdx.x, ocg = blockIdx.y, b = blockIdx.z;
    const int ty0 = (tile / 6) * 16, tx0 = (tile % 6) * 16;
    const float* xb = x + (size_t)b * CIN * NP;

    // x tile staging: thread owns halo positions, loops channels (cheap addr)
    for (int pos = tid; pos < 324; pos += 256) {
        const int yy = pos / 18, xx = pos - yy * 18;
        const int gy = ty0 - 1 + yy, gx = tx0 - 1 + xx;
        const bool ok = ((unsigned)gy < (unsigned)H0) && ((unsigned)gx < (unsigned)H0);
        const int gidx = gy * H0 + gx;
        #pragma unroll 3
        for (int ic = 0; ic < CIN; ic++)
            xs[ic * 360 + yy * 20 + xx] = ok ? xb[ic * NP + gidx] : 0.f;
    }
    // weight staging (transposed)
    for (int i = tid; i < 189 * 32; i += 256) {
        const int ict = i >> 5, oc = i & 31;
        const int oc96 = ocg * 32 + oc;
        wt[i] = (oc96 < 48) ? w1o[oc96 * 189 + ict] : w1g[(oc96 - 48) * 189 + ict];
    }
    if (tid < 32) {
        const int oc96 = ocg * 32 + tid;
        bs[tid] = (oc96 < 48) ? b1o[oc96] : b1g[oc96 - 48];
    }
    __syncthreads();

    const int og = tid >> 6;            // wave id -> 8 oc
    const int q  = tid & 63;            // quad id: 16 rows x 4 quad-cols
    const int qy = q >> 2, qx4 = (q & 3) * 4;
    const int oc8 = og * 8;

    float acc[4][8];
    #pragma unroll
    for (int i = 0; i < 4; i++)
        #pragma unroll
        for (int j = 0; j < 8; j++) acc[i][j] = bs[oc8 + j];

    for (int ic = 0; ic < CIN; ic++) {
        #pragma unroll
        for (int ky = 0; ky < 3; ky++) {
            const float4 f0 = *(const float4*)&xs[ic * 360 + (qy + ky) * 20 + qx4];
            const float4 f1 = *(const float4*)&xs[ic * 360 + (qy + ky) * 20 + qx4 + 4];
            const float xw[8] = {f0.x, f0.y, f0.z, f0.w, f1.x, f1.y, f1.z, f1.w};
            #pragma unroll
            for (int kx = 0; kx < 3; kx++) {
                const float4 wa = *(const float4*)&wt[(ic * 9 + ky * 3 + kx) * 32 + oc8];
                const float4 wb = *(const float4*)&wt[(ic * 9 + ky * 3 + kx) * 32 + oc8 + 4];
                const float wv[8] = {wa.x, wa.y, wa.z, wa.w, wb.x, wb.y, wb.z, wb.w};
                #pragma unroll
                for (int i = 0; i < 4; i++)
                    #pragma unroll
                    for (int j = 0; j < 8; j++)
                        acc[i][j] = fmaf(xw[i + kx], wv[j], acc[i][j]);
            }
        }
    }

    const int oy = ty0 + qy;
    if (oy < H0) {
        #pragma unroll
        for (int j = 0; j < 8; j++) {
            const int oc96 = ocg * 32 + oc8 + j;    // wave-uniform
            float* base = (oc96 < 48)
                ? hid_o + ((size_t)b * HIDC + oc96) * NP
                : hid_g + ((size_t)b * HIDC + (oc96 - 48)) * NP;
            #pragma unroll
            for (int i = 0; i < 4; i++) {
                const int ox = tx0 + qx4 + i;
                if (ox < H0) base[oy * H0 + ox] = fmaxf(acc[i][j], 0.f);
            }
        }
    }
}

// ---------------------------------------------------------------------------
// K2 v3: conv2 both heads (48->8 dirs, 48->1 gate) + full mask epilogue.
// Block: 16x16 tile. Thread: 4 px x output-slice (slice s owns dirs 2s,2s+1;
// slice 3 also owns the gate). Channels staged 12 at a time (4 rounds) for
// both heads; weights transposed in LDS. Exchange via LDS, then per-px
// epilogue with coalesced stores. No spills (~50 VGPR).
// ---------------------------------------------------------------------------
__global__ __launch_bounds__(256) void k2_conv2_masks(
    const float* __restrict__ hid_o, const float* __restrict__ hid_g,
    const float* __restrict__ w2o, const float* __restrict__ b2o,
    const float* __restrict__ w2g, const float* __restrict__ b2g,
    float* __restrict__ v_out,
    float* __restrict__ g_buf, float* __restrict__ m_lp, float* __restrict__ m_hp)
{
    __shared__ __align__(16) float ho_s[12 * 18 * 20];  // chunk of head_o
    __shared__ __align__(16) float hg_s[12 * 18 * 20];  // chunk of head_g
    __shared__ __align__(16) float wo_s[HIDC * 9 * 8];  // [(ic*9+tap)*8 + d]
    __shared__ float wg_s[HIDC * 9];
    __shared__ float ex[256 * 9];                       // px-major exchange
    const int tid = threadIdx.x;
    const int tile = blockIdx.x, b = blockIdx.y;
    const int ty0 = (tile / 6) * 16, tx0 = (tile % 6) * 16;

    // stage transposed weights once
    for (int i = tid; i < HIDC * 9 * 8; i += 256) {
        const int d = i / (HIDC * 9), r = i - d * (HIDC * 9);
        wo_s[r * 8 + d] = w2o[i];
    }
    for (int i = tid; i < HIDC * 9; i += 256) wg_s[i] = w2g[i];

    const int q  = tid >> 2;            // quad 0..63: 16 rows x 4 quad-cols
    const int s  = tid & 3;             // output slice
    const int qy = q >> 2, qx4 = (q & 3) * 4;
    const bool s3 = (s == 3);

    float acc[4][2];
    float accg[4];
    #pragma unroll
    for (int i = 0; i < 4; i++) { acc[i][0] = 0.f; acc[i][1] = 0.f; accg[i] = 0.f; }

    // halo position owned by this thread for staging
    for (int r = 0; r < 4; r++) {
        const int cb = r * 12;
        __syncthreads();   // protects buffer reuse (and orders weight staging r==0)
        for (int pos = tid; pos < 324; pos += 256) {
            const int yy = pos / 18, xx = pos - yy * 18;
            const int gy = ty0 - 1 + yy, gx = tx0 - 1 + xx;
            const bool ok = ((unsigned)gy < (unsigned)H0) && ((unsigned)gx < (unsigned)H0);
            const int gidx = gy * H0 + gx;
            const float* po = hid_o + ((size_t)b * HIDC + cb) * NP + gidx;
            const float* pg = hid_g + ((size_t)b * HIDC + cb) * NP + gidx;
            const int lbase = yy * 20 + xx;
            #pragma unroll 3
            for (int ch = 0; ch < 12; ch++) {
                ho_s[ch * 360 + lbase] = ok ? po[ch * NP] : 0.f;
                hg_s[ch * 360 + lbase] = ok ? pg[ch * NP] : 0.f;
            }
        }
        __syncthreads();
        for (int ic = 0; ic < 12; ic++) {
            const int icg = cb + ic;
            #pragma unroll
            for (int ky = 0; ky < 3; ky++) {
                const int lrow = ic * 360 + (qy + ky) * 20 + qx4;
                const float4 f0 = *(const float4*)&ho_s[lrow];
                const float4 f1 = *(const float4*)&ho_s[lrow + 4];
                const float xw[8] = {f0.x, f0.y, f0.z, f0.w, f1.x, f1.y, f1.z, f1.w};
                float gw[8];
                if (s3) {
                    const float4 g0 = *(const float4*)&hg_s[lrow];
                    const float4 g1 = *(const float4*)&hg_s[lrow + 4];
                    gw[0]=g0.x; gw[1]=g0.y; gw[2]=g0.z; gw[3]=g0.w;
                    gw[4]=g1.x; gw[5]=g1.y; gw[6]=g1.z; gw[7]=g1.w;
                }
                #pragma unroll
                for (int kx = 0; kx < 3; kx++) {
                    const int tap = ky * 3 + kx;
                    const float2 wv = ((const float2*)wo_s)[(icg * 9 + tap) * 4 + s];
                    #pragma unroll
                    for (int i = 0; i < 4; i++) {
                        acc[i][0] = fmaf(xw[i + kx], wv.x, acc[i][0]);
                        acc[i][1] = fmaf(xw[i + kx], wv.y, acc[i][1]);
                    }
                    if (s3) {
                        const float wgv = wg_s[icg * 9 + tap];
                        #pragma unroll
                        for (int i = 0; i < 4; i++)
                            accg[i] = fmaf(gw[i + kx], wgv, accg[i]);
                    }
                }
            }
        }
    }

    // exchange: write my outputs px-major, read back per-pixel
    #pragma unroll
    for (int i = 0; i < 4; i++) {
        const int pxl = q * 4 + i;
        ex[pxl * 9 + 2 * s]     = acc[i][0];
        ex[pxl * 9 + 2 * s + 1] = acc[i][1];
        if (s3) ex[pxl * 9 + 8] = accg[i];
    }
    __syncthreads();

    const int py = tid >> 4, pxc = tid & 15;
    const int oy = ty0 + py, ox = tx0 + pxc;
    if (oy >= H0 || ox >= H0) return;
    const int pix = oy * H0 + ox;

    float v[8];
    #pragma unroll
    for (int d = 0; d < 8; d++) v[d] = tanh_fast(ex[tid * 9 + d] + b2o[d]);
    const float g = 1.f / (1.f + __expf(-(ex[tid * 9 + 8] + b2g[0])));

    constexpr float DT[8][9] = {
        {-1, 0, 1, -1, 0, 1, -1, 0, 1},
        {-1,-1, 0, -1, 0, 1,  0, 1, 1},
        {-1,-1,-1,  0, 0, 0,  1, 1, 1},
        { 0,-1,-1,  1, 0,-1,  1, 1, 0},
        { 1, 0,-1,  1, 0,-1,  1, 0,-1},
        { 1, 1, 0,  1, 0,-1,  0,-1,-1},
        { 1, 1, 1,  0, 0, 0, -1,-1,-1},
        { 0, 1, 1, -1, 0, 1, -1,-1, 0}};
    float ker[9];
    #pragma unroll
    for (int n = 0; n < 9; n++) {
        float t = 0.f;
        #pragma unroll
        for (int d = 0; d < 8; d++) t += v[d] * DT[d][n];
        ker[n] = -0.125f * t;
    }
    ker[4] += 2.5f;
    float mx = ker[0];
    #pragma unroll
    for (int n = 1; n < 9; n++) mx = fmaxf(mx, ker[n]);
    float exn[9], sum = 0.f;
    #pragma unroll
    for (int n = 0; n < 9; n++) { exn[n] = __expf((ker[n] - mx) * 2.0f); sum += exn[n]; }
    const float rs = 1.f / sum;
    float mean = 0.f;
    #pragma unroll
    for (int n = 0; n < 9; n++) mean += ker[n];
    mean *= (1.f / 9.f);
    float den = 1e-8f;
    #pragma unroll
    for (int n = 0; n < 9; n++) den += fabsf(ker[n] - mean);
    const float rd = 1.f / den;

    #pragma unroll
    for (int d = 0; d < 8; d++) v_out[((size_t)b * 8 + d) * NP + pix] = v[d];
    g_buf[(size_t)b * NP + pix] = g;
    #pragma unroll
    for (int n = 0; n < 9; n++) {
        m_lp[((size_t)b * 9 + n) * NP + pix] = exn[n] * rs;
        m_hp[((size_t)b * 9 + n) * NP + pix] = (ker[n] - mean) * rd;
    }
}

// ---------------------------------------------------------------------------
// K3: low-res 9-tap aggregation (reflect pad), thread = (b, c, pixel).
// ---------------------------------------------------------------------------
__global__ __launch_bounds__(256) void k3_agg(
    const float* __restrict__ x, const float* __restrict__ m_lp,
    const float* __restrict__ m_hp,
    float* __restrict__ a_lp, float* __restrict__ a_hp)
{
    const int pix = blockIdx.x * 256 + threadIdx.x;
    if (pix >= NP) return;
    const int c = blockIdx.y, b = blockIdx.z;
    const int oy = pix / H0, ox = pix - oy * H0;
    float ml[9], mh[9];
    const float* mlb = m_lp + (size_t)b * 9 * NP + pix;
    const float* mhb = m_hp + (size_t)b * 9 * NP + pix;
    #pragma unroll
    for (int n = 0; n < 9; n++) { ml[n] = mlb[n * NP]; mh[n] = mhb[n * NP]; }
    const float* xc = x + ((size_t)b * CIN + c) * NP;
    float alp = 0.f, ahp = 0.f;
    #pragma unroll
    for (int ky = 0; ky < 3; ky++) {
        int iy = oy + ky - 1;
        iy = iy < 0 ? -iy : (iy > H0 - 1 ? 2 * (H0 - 1) - iy : iy);
        #pragma unroll
        for (int kx = 0; kx < 3; kx++) {
            int ix = ox + kx - 1;
            ix = ix < 0 ? -ix : (ix > H0 - 1 ? 2 * (H0 - 1) - ix : ix);
            const float p = xc[iy * H0 + ix];
            const int n = ky * 3 + kx;
            alp = fmaf(p, ml[n], alp);
            ahp = fmaf(p, mh[n], ahp);
        }
    }
    a_lp[((size_t)b * CIN + c) * NP + pix] = alp;
    a_hp[((size_t)b * CIN + c) * NP + pix] = ahp;
}

// ---------------------------------------------------------------------------
// K4: hi-res blend. One thread = one float4 of an output row; repeat index
// W>>2 constant within the float4 so agg/g/lam are scalars; only bilinear
// x_up varies. blockIdx.y==CIN writes g_up.
// ---------------------------------------------------------------------------
__global__ __launch_bounds__(256) void k4_up(
    const float* __restrict__ x, const float* __restrict__ g_buf,
    const float* __restrict__ a_lp, const float* __restrict__ a_hp,
    const float* __restrict__ beta,
    float* __restrict__ y_out, float* __restrict__ gup_out)
{
    const int tid = threadIdx.x;
    if (tid >= 243) return;
    const int c = blockIdx.y;              // 0..20 = channel, 21 = g_up
    const int b = blockIdx.z;
    const int H = blockIdx.x * 3 + tid / 81;
    const int wq = tid % 81;
    const int h0r = H >> 2;
    const float g = g_buf[(size_t)b * NP + h0r * H0 + wq];
    if (c == CIN) {
        *reinterpret_cast<float4*>(gup_out + (size_t)b * NPH + H * HH + wq * 4) =
            make_float4(g, g, g, g);
        return;
    }
    const float tb = tanh_fast(beta[0]);
    const float alp = a_lp[((size_t)b * CIN + c) * NP + h0r * H0 + wq];
    const float ahp = a_hp[((size_t)b * CIN + c) * NP + h0r * H0 + wq];
    const float lam = 0.15f * (1.f - g);
    const float gh = tb * g;
    const float* xc = x + ((size_t)b * CIN + c) * NP;
    const float ysf = (float)H * (80.f / 323.f);
    int y0 = (int)ysf;
    if (y0 > H0 - 2) y0 = H0 - 2;
    const float wy = ysf - (float)y0;
    const float* r0 = xc + y0 * H0;
    const float* r1 = r0 + H0;
    float res[4];
    #pragma unroll
    for (int i = 0; i < 4; i++) {
        const int W = wq * 4 + i;
        const float xsf = (float)W * (80.f / 323.f);
        int x0 = (int)xsf;
        if (x0 > H0 - 2) x0 = H0 - 2;
        const float wx = xsf - (float)x0;
        const float x00 = r0[x0], x01 = r0[x0 + 1];
        const float x10 = r1[x0], x11 = r1[x0 + 1];
        const float top = x00 + (x01 - x00) * wx;
        const float bot = x10 + (x11 - x10) * wx;
        const float xup = top + (bot - top) * wy;
        res[i] = xup + lam * (alp - xup) + gh * ahp;
    }
    *reinterpret_cast<float4*>(y_out + ((size_t)b * CIN + c) * NPH + H * HH + wq * 4) =
        make_float4(res[0], res[1], res[2], res[3]);
}

// ---------------------------------------------------------------------------
extern "C" void kernel_launch(void* const* d_in, const int* in_sizes, int n_in,
                              void* d_out, int out_size, void* d_ws, size_t ws_size,
                              hipStream_t stream)
{
    const float* x    = (const float*)d_in[0];
    const float* w1o  = (const float*)d_in[1];
    const float* b1o  = (const float*)d_in[2];
    const float* w2o  = (const float*)d_in[3];
    const float* b2o  = (const float*)d_in[4];
    const float* w1g  = (const float*)d_in[5];
    const float* b1g  = (const float*)d_in[6];
    const float* w2g  = (const float*)d_in[7];
    const float* b2g  = (const float*)d_in[8];
    const float* beta = (const float*)d_in[9];
    float* out = (float*)d_out;
    float* wsf = (float*)d_ws;

    float* hid_o = wsf;
    float* hid_g = hid_o + (size_t)B_N * HIDC * NP;
    float* m_lp  = hid_g + (size_t)B_N * HIDC * NP;
    float* m_hp  = m_lp + (size_t)B_N * 9 * NP;
    float* g_buf = m_hp + (size_t)B_N * 9 * NP;
    float* a_lp  = g_buf + (size_t)B_N * NP;
    float* a_hp  = a_lp + (size_t)B_N * CIN * NP;

    // output layout: y [4,21,324,324], v [4,8,81,81], g_up [4,1,324,324]
    float* y_out = out;
    float* v_out = out + (size_t)B_N * CIN * NPH;
    float* gup   = v_out + (size_t)B_N * 8 * NP;

    k1_conv1<<<dim3(36, 3, B_N), 256, 0, stream>>>(x, w1o, b1o, w1g, b1g, hid_o, hid_g);
    k2_conv2_masks<<<dim3(36, B_N), 256, 0, stream>>>(
        hid_o, hid_g, w2o, b2o, w2g, b2g, v_out, g_buf, m_lp, m_hp);
    k3_agg<<<dim3((NP + 255) / 256, CIN, B_N), 256, 0, stream>>>(x, m_lp, m_hp, a_lp, a_hp);
    k4_up<<<dim3(108, CIN + 1, B_N), 256, 0, stream>>>(x, g_buf, a_lp, a_hp, beta, y_out, gup);
}

// Round 4
// 171.856 us; speedup vs baseline: 1.4028x; 1.2968x over previous
//
#include <hip/hip_runtime.h>
#include <math.h>

// Problem constants
#define B_N   4
#define CIN   21
#define HIDC  48
#define H0    81
#define NP    6561      // 81*81
#define HH    324
#define NPH   104976    // 324*324

__device__ __forceinline__ float tanh_fast(float x) {
    float e = __expf(2.f * x);
    return 1.f - 2.f / (e + 1.f);
}

// ---------------------------------------------------------------------------
// K1 v4: conv1 both heads (21 -> 96 = 48 o + 48 g), relu.
// Grid (36 tiles, 6 oc-groups of 16, B). Block: 16x16 px tile; thread:
// 4 px x 4 oc (wave w owns oc 4w..4w+3). Weights transposed in LDS
// [ic*9+tap][16]; x tile row-padded to 20 for aligned b128.
// ---------------------------------------------------------------------------
__global__ __launch_bounds__(256) void k1_conv1(
    const float* __restrict__ x,
    const float* __restrict__ w1o, const float* __restrict__ b1o,
    const float* __restrict__ w1g, const float* __restrict__ b1g,
    float* __restrict__ hid_o, float* __restrict__ hid_g)
{
    __shared__ __align__(16) float xs[CIN * 18 * 20];   // [ic][yy][xx(pad 20)]
    __shared__ __align__(16) float wt[189 * 16];        // [(ic*9+tap)*16 + oc]
    __shared__ float bs[16];
    const int tid = threadIdx.x;
    const int tile = blockIdx.x, ocg = blockIdx.y, b = blockIdx.z;
    const int ty0 = (tile / 6) * 16, tx0 = (tile % 6) * 16;
    const float* xb = x + (size_t)b * CIN * NP;

    for (int pos = tid; pos < 324; pos += 256) {
        const int yy = pos / 18, xx = pos - yy * 18;
        const int gy = ty0 - 1 + yy, gx = tx0 - 1 + xx;
        const bool ok = ((unsigned)gy < (unsigned)H0) && ((unsigned)gx < (unsigned)H0);
        const int gidx = gy * H0 + gx;
        #pragma unroll 3
        for (int ic = 0; ic < CIN; ic++)
            xs[ic * 360 + yy * 20 + xx] = ok ? xb[ic * NP + gidx] : 0.f;
    }
    for (int i = tid; i < 189 * 16; i += 256) {
        const int ict = i >> 4, oc = i & 15;
        const int oc96 = ocg * 16 + oc;
        wt[i] = (oc96 < 48) ? w1o[oc96 * 189 + ict] : w1g[(oc96 - 48) * 189 + ict];
    }
    if (tid < 16) {
        const int oc96 = ocg * 16 + tid;
        bs[tid] = (oc96 < 48) ? b1o[oc96] : b1g[oc96 - 48];
    }
    __syncthreads();

    const int og = tid >> 6;            // wave -> 4 oc
    const int q  = tid & 63;
    const int qy = q >> 2, qx4 = (q & 3) * 4;
    const int oc4 = og * 4;

    float acc[4][4];
    #pragma unroll
    for (int i = 0; i < 4; i++)
        #pragma unroll
        for (int j = 0; j < 4; j++) acc[i][j] = bs[oc4 + j];

    for (int ic = 0; ic < CIN; ic++) {
        #pragma unroll
        for (int ky = 0; ky < 3; ky++) {
            const float4 f0 = *(const float4*)&xs[ic * 360 + (qy + ky) * 20 + qx4];
            const float4 f1 = *(const float4*)&xs[ic * 360 + (qy + ky) * 20 + qx4 + 4];
            const float xw[8] = {f0.x, f0.y, f0.z, f0.w, f1.x, f1.y, f1.z, f1.w};
            #pragma unroll
            for (int kx = 0; kx < 3; kx++) {
                const float4 wv = *(const float4*)&wt[(ic * 9 + ky * 3 + kx) * 16 + oc4];
                const float wj[4] = {wv.x, wv.y, wv.z, wv.w};
                #pragma unroll
                for (int i = 0; i < 4; i++)
                    #pragma unroll
                    for (int j = 0; j < 4; j++)
                        acc[i][j] = fmaf(xw[i + kx], wj[j], acc[i][j]);
            }
        }
    }

    const int oy = ty0 + qy;
    if (oy < H0) {
        #pragma unroll
        for (int j = 0; j < 4; j++) {
            const int oc96 = ocg * 16 + oc4 + j;    // wave-uniform
            float* base = (oc96 < 48)
                ? hid_o + ((size_t)b * HIDC + oc96) * NP
                : hid_g + ((size_t)b * HIDC + (oc96 - 48)) * NP;
            #pragma unroll
            for (int i = 0; i < 4; i++) {
                const int ox = tx0 + qx4 + i;
                if (ox < H0) base[oy * H0 + ox] = fmaxf(acc[i][j], 0.f);
            }
        }
    }
}

// ---------------------------------------------------------------------------
// K2 v4: conv2 both heads + mask epilogue, MLP-first design.
// Block = 256 thr: px = tid&31 (32 consecutive pixels, coalesced loads),
// slice = tid>>5 (8 slices x 6 ic). Each thread: 54 taps x 2 heads = 108
// independent global loads straight from L2 (no staging barrier), 9 accs.
// Reduce: shfl_xor(32) then LDS across 4 waves. Epilogue on 32 lanes,
// coalesced plane-major stores via LDS bounce. Grid 206 x B = 824 blocks.
// ---------------------------------------------------------------------------
__global__ __launch_bounds__(256) void k2_conv2_masks(
    const float* __restrict__ hid_o, const float* __restrict__ hid_g,
    const float* __restrict__ w2o, const float* __restrict__ b2o,
    const float* __restrict__ w2g, const float* __restrict__ b2g,
    float* __restrict__ v_out,
    float* __restrict__ g_buf, float* __restrict__ m_lp, float* __restrict__ m_hp)
{
    __shared__ __align__(16) float wo_s[HIDC * 9 * 8];  // [(ic*9+tap)*8 + d]
    __shared__ float wg_s[HIDC * 9];
    __shared__ float red[4][32][12];                    // wave-partials, pad 12
    __shared__ float res_s[32][28];                     // 27 outputs per px
    const int tid = threadIdx.x;
    const int b = blockIdx.y;

    for (int i = tid; i < HIDC * 9 * 8; i += 256) {
        const int d = i / (HIDC * 9), r = i - d * (HIDC * 9);
        wo_s[r * 8 + d] = w2o[i];
    }
    for (int i = tid; i < HIDC * 9; i += 256) wg_s[i] = w2g[i];
    __syncthreads();

    const int pxl = tid & 31;
    const int s   = tid >> 5;                // 0..7
    const int w   = tid >> 6;                // wave
    const int px  = blockIdx.x * 32 + pxl;
    const bool valid = (px < NP);
    const int oy = px / H0, ox = px - oy * H0;
    const int ic0 = s * 6;
    const float* po = hid_o + ((size_t)b * HIDC + ic0) * NP;
    const float* pg = hid_g + ((size_t)b * HIDC + ic0) * NP;

    float a[8] = {0.f, 0.f, 0.f, 0.f, 0.f, 0.f, 0.f, 0.f};
    float ag = 0.f;

    #pragma unroll 1
    for (int ky = 0; ky < 3; ky++) {
        const int iy = oy + ky - 1;
        const bool rok = valid && ((unsigned)iy < (unsigned)H0);
        #pragma unroll
        for (int kx = 0; kx < 3; kx++) {
            const int ix = ox + kx - 1;
            const bool ok = rok && ((unsigned)ix < (unsigned)H0);
            const int off = iy * H0 + ix;
            const int tap = ky * 3 + kx;
            #pragma unroll
            for (int j = 0; j < 6; j++) {
                const float vo = ok ? po[j * NP + off] : 0.f;
                const float vg = ok ? pg[j * NP + off] : 0.f;
                const int wb = ((ic0 + j) * 9 + tap) * 8;
                const float4 wA = *(const float4*)&wo_s[wb];
                const float4 wB = *(const float4*)&wo_s[wb + 4];
                a[0] = fmaf(vo, wA.x, a[0]); a[1] = fmaf(vo, wA.y, a[1]);
                a[2] = fmaf(vo, wA.z, a[2]); a[3] = fmaf(vo, wA.w, a[3]);
                a[4] = fmaf(vo, wB.x, a[4]); a[5] = fmaf(vo, wB.y, a[5]);
                a[6] = fmaf(vo, wB.z, a[6]); a[7] = fmaf(vo, wB.w, a[7]);
                ag = fmaf(vg, wg_s[(ic0 + j) * 9 + tap], ag);
            }
        }
    }

    // sum slice-pairs within wave (lane^32 = other slice, same px)
    #pragma unroll
    for (int n = 0; n < 8; n++) a[n] += __shfl_xor(a[n], 32);
    ag += __shfl_xor(ag, 32);
    if ((tid & 32) == 0) {
        #pragma unroll
        for (int n = 0; n < 8; n++) red[w][pxl][n] = a[n];
        red[w][pxl][8] = ag;
    }
    __syncthreads();

    if (tid < 32 && valid) {
        float v[8];
        #pragma unroll
        for (int n = 0; n < 8; n++)
            v[n] = tanh_fast(red[0][tid][n] + red[1][tid][n] + red[2][tid][n]
                             + red[3][tid][n] + b2o[n]);
        const float agf = red[0][tid][8] + red[1][tid][8] + red[2][tid][8]
                        + red[3][tid][8] + b2g[0];
        const float g = 1.f / (1.f + __expf(-agf));

        constexpr float DT[8][9] = {
            {-1, 0, 1, -1, 0, 1, -1, 0, 1},
            {-1,-1, 0, -1, 0, 1,  0, 1, 1},
            {-1,-1,-1,  0, 0, 0,  1, 1, 1},
            { 0,-1,-1,  1, 0,-1,  1, 1, 0},
            { 1, 0,-1,  1, 0,-1,  1, 0,-1},
            { 1, 1, 0,  1, 0,-1,  0,-1,-1},
            { 1, 1, 1,  0, 0, 0, -1,-1,-1},
            { 0, 1, 1, -1, 0, 1, -1,-1, 0}};
        float ker[9];
        #pragma unroll
        for (int n = 0; n < 9; n++) {
            float t = 0.f;
            #pragma unroll
            for (int d = 0; d < 8; d++) t += v[d] * DT[d][n];
            ker[n] = -0.125f * t;
        }
        ker[4] += 2.5f;
        float mx = ker[0];
        #pragma unroll
        for (int n = 1; n < 9; n++) mx = fmaxf(mx, ker[n]);
        float exn[9], sum = 0.f;
        #pragma unroll
        for (int n = 0; n < 9; n++) { exn[n] = __expf((ker[n] - mx) * 2.0f); sum += exn[n]; }
        const float rs = 1.f / sum;
        float mean = 0.f;
        #pragma unroll
        for (int n = 0; n < 9; n++) mean += ker[n];
        mean *= (1.f / 9.f);
        float den = 1e-8f;
        #pragma unroll
        for (int n = 0; n < 9; n++) den += fabsf(ker[n] - mean);
        const float rd = 1.f / den;

        #pragma unroll
        for (int n = 0; n < 8; n++) res_s[tid][n] = v[n];
        res_s[tid][8] = g;
        #pragma unroll
        for (int n = 0; n < 9; n++) {
            res_s[tid][9 + n]  = exn[n] * rs;
            res_s[tid][18 + n] = (ker[n] - mean) * rd;
        }
    }
    __syncthreads();

    // coalesced plane-major stores
    const int px0 = blockIdx.x * 32;
    for (int j = tid; j < 27 * 32; j += 256) {
        const int plane = j >> 5, pl = j & 31;
        const int p = px0 + pl;
        if (p >= NP) continue;
        const float val = res_s[pl][plane];
        float* dst;
        if (plane < 8)        dst = v_out + ((size_t)b * 8 + plane) * NP;
        else if (plane == 8)  dst = g_buf + (size_t)b * NP;
        else if (plane < 18)  dst = m_lp + ((size_t)b * 9 + (plane - 9)) * NP;
        else                  dst = m_hp + ((size_t)b * 9 + (plane - 18)) * NP;
        dst[p] = val;
    }
}

// ---------------------------------------------------------------------------
// K3: low-res 9-tap aggregation (reflect pad), thread = (b, c, pixel).
// ---------------------------------------------------------------------------
__global__ __launch_bounds__(256) void k3_agg(
    const float* __restrict__ x, const float* __restrict__ m_lp,
    const float* __restrict__ m_hp,
    float* __restrict__ a_lp, float* __restrict__ a_hp)
{
    const int pix = blockIdx.x * 256 + threadIdx.x;
    if (pix >= NP) return;
    const int c = blockIdx.y, b = blockIdx.z;
    const int oy = pix / H0, ox = pix - oy * H0;
    float ml[9], mh[9];
    const float* mlb = m_lp + (size_t)b * 9 * NP + pix;
    const float* mhb = m_hp + (size_t)b * 9 * NP + pix;
    #pragma unroll
    for (int n = 0; n < 9; n++) { ml[n] = mlb[n * NP]; mh[n] = mhb[n * NP]; }
    const float* xc = x + ((size_t)b * CIN + c) * NP;
    float alp = 0.f, ahp = 0.f;
    #pragma unroll
    for (int ky = 0; ky < 3; ky++) {
        int iy = oy + ky - 1;
        iy = iy < 0 ? -iy : (iy > H0 - 1 ? 2 * (H0 - 1) - iy : iy);
        #pragma unroll
        for (int kx = 0; kx < 3; kx++) {
            int ix = ox + kx - 1;
            ix = ix < 0 ? -ix : (ix > H0 - 1 ? 2 * (H0 - 1) - ix : ix);
            const float p = xc[iy * H0 + ix];
            const int n = ky * 3 + kx;
            alp = fmaf(p, ml[n], alp);
            ahp = fmaf(p, mh[n], ahp);
        }
    }
    a_lp[((size_t)b * CIN + c) * NP + pix] = alp;
    a_hp[((size_t)b * CIN + c) * NP + pix] = ahp;
}

// ---------------------------------------------------------------------------
// K4: hi-res blend. One thread = one float4 of an output row; repeat index
// W>>2 constant within the float4 so agg/g/lam are scalars; only bilinear
// x_up varies. blockIdx.y==CIN writes g_up.
// ---------------------------------------------------------------------------
__global__ __launch_bounds__(256) void k4_up(
    const float* __restrict__ x, const float* __restrict__ g_buf,
    const float* __restrict__ a_lp, const float* __restrict__ a_hp,
    const float* __restrict__ beta,
    float* __restrict__ y_out, float* __restrict__ gup_out)
{
    const int tid = threadIdx.x;
    if (tid >= 243) return;
    const int c = blockIdx.y;              // 0..20 = channel, 21 = g_up
    const int b = blockIdx.z;
    const int H = blockIdx.x * 3 + tid / 81;
    const int wq = tid % 81;
    const int h0r = H >> 2;
    const float g = g_buf[(size_t)b * NP + h0r * H0 + wq];
    if (c == CIN) {
        *reinterpret_cast<float4*>(gup_out + (size_t)b * NPH + H * HH + wq * 4) =
            make_float4(g, g, g, g);
        return;
    }
    const float tb = tanh_fast(beta[0]);
    const float alp = a_lp[((size_t)b * CIN + c) * NP + h0r * H0 + wq];
    const float ahp = a_hp[((size_t)b * CIN + c) * NP + h0r * H0 + wq];
    const float lam = 0.15f * (1.f - g);
    const float gh = tb * g;
    const float* xc = x + ((size_t)b * CIN + c) * NP;
    const float ysf = (float)H * (80.f / 323.f);
    int y0 = (int)ysf;
    if (y0 > H0 - 2) y0 = H0 - 2;
    const float wy = ysf - (float)y0;
    const float* r0 = xc + y0 * H0;
    const float* r1 = r0 + H0;
    float res[4];
    #pragma unroll
    for (int i = 0; i < 4; i++) {
        const int W = wq * 4 + i;
        const float xsf = (float)W * (80.f / 323.f);
        int x0 = (int)xsf;
        if (x0 > H0 - 2) x0 = H0 - 2;
        const float wx = xsf - (float)x0;
        const float x00 = r0[x0], x01 = r0[x0 + 1];
        const float x10 = r1[x0], x11 = r1[x0 + 1];
        const float top = x00 + (x01 - x00) * wx;
        const float bot = x10 + (x11 - x10) * wx;
        const float xup = top + (bot - top) * wy;
        res[i] = xup + lam * (alp - xup) + gh * ahp;
    }
    *reinterpret_cast<float4*>(y_out + ((size_t)b * CIN + c) * NPH + H * HH + wq * 4) =
        make_float4(res[0], res[1], res[2], res[3]);
}

// ---------------------------------------------------------------------------
extern "C" void kernel_launch(void* const* d_in, const int* in_sizes, int n_in,
                              void* d_out, int out_size, void* d_ws, size_t ws_size,
                              hipStream_t stream)
{
    const float* x    = (const float*)d_in[0];
    const float* w1o  = (const float*)d_in[1];
    const float* b1o  = (const float*)d_in[2];
    const float* w2o  = (const float*)d_in[3];
    const float* b2o  = (const float*)d_in[4];
    const float* w1g  = (const float*)d_in[5];
    const float* b1g  = (const float*)d_in[6];
    const float* w2g  = (const float*)d_in[7];
    const float* b2g  = (const float*)d_in[8];
    const float* beta = (const float*)d_in[9];
    float* out = (float*)d_out;
    float* wsf = (float*)d_ws;

    float* hid_o = wsf;
    float* hid_g = hid_o + (size_t)B_N * HIDC * NP;
    float* m_lp  = hid_g + (size_t)B_N * HIDC * NP;
    float* m_hp  = m_lp + (size_t)B_N * 9 * NP;
    float* g_buf = m_hp + (size_t)B_N * 9 * NP;
    float* a_lp  = g_buf + (size_t)B_N * NP;
    float* a_hp  = a_lp + (size_t)B_N * CIN * NP;

    // output layout: y [4,21,324,324], v [4,8,81,81], g_up [4,1,324,324]
    float* y_out = out;
    float* v_out = out + (size_t)B_N * CIN * NPH;
    float* gup   = v_out + (size_t)B_N * 8 * NP;

    k1_conv1<<<dim3(36, 6, B_N), 256, 0, stream>>>(x, w1o, b1o, w1g, b1g, hid_o, hid_g);
    k2_conv2_masks<<<dim3((NP + 31) / 32, B_N), 256, 0, stream>>>(
        hid_o, hid_g, w2o, b2o, w2g, b2g, v_out, g_buf, m_lp, m_hp);
    k3_agg<<<dim3((NP + 255) / 256, CIN, B_N), 256, 0, stream>>>(x, m_lp, m_hp, a_lp, a_hp);
    k4_up<<<dim3(108, CIN + 1, B_N), 256, 0, stream>>>(x, g_buf, a_lp, a_hp, beta, y_out, gup);
}

// Round 5
// 153.831 us; speedup vs baseline: 1.5672x; 1.1172x over previous
//
#include <hip/hip_runtime.h>
#include <math.h>

// Problem constants
#define B_N   4
#define CIN   21
#define HIDC  48
#define H0    81
#define NP    6561      // 81*81
#define HH    324
#define NPH   104976    // 324*324

__device__ __forceinline__ float tanh_fast(float x) {
    float e = __expf(2.f * x);
    return 1.f - 2.f / (e + 1.f);
}

// ---------------------------------------------------------------------------
// K1 v5: conv1 both heads (21 -> 96 = 48 o + 48 g), relu.
// Grid (36 tiles, 3 oc-groups of 32, B). Block 256 = 16x16 px tile.
// Thread = 4 px (row quad) x 8 oc (wave-uniform oc octet -> LDS broadcast).
// 32 accs/thread: LDS traffic per FMA is 3.2x lower than v4 (the v4
// bottleneck: LDS pipe shared by 4 SIMDs saturated at 4 oc/thread).
// ---------------------------------------------------------------------------
__global__ __launch_bounds__(256) void k1_conv1(
    const float* __restrict__ x,
    const float* __restrict__ w1o, const float* __restrict__ b1o,
    const float* __restrict__ w1g, const float* __restrict__ b1g,
    float* __restrict__ hid_o, float* __restrict__ hid_g)
{
    __shared__ __align__(16) float xs[CIN * 18 * 20];   // [ic][yy][xx(pad 20)]
    __shared__ __align__(16) float wt[189 * 32];        // [(ic*9+tap)*32 + oc]
    __shared__ float bs[32];
    const int tid = threadIdx.x;
    const int tile = blockIdx.x, ocg = blockIdx.y, b = blockIdx.z;
    const int ty0 = (tile / 6) * 16, tx0 = (tile % 6) * 16;
    const float* xb = x + (size_t)b * CIN * NP;

    for (int pos = tid; pos < 324; pos += 256) {
        const int yy = pos / 18, xx = pos - yy * 18;
        const int gy = ty0 - 1 + yy, gx = tx0 - 1 + xx;
        const bool ok = ((unsigned)gy < (unsigned)H0) && ((unsigned)gx < (unsigned)H0);
        const int gidx = gy * H0 + gx;
        #pragma unroll 3
        for (int ic = 0; ic < CIN; ic++)
            xs[ic * 360 + yy * 20 + xx] = ok ? xb[ic * NP + gidx] : 0.f;
    }
    for (int i = tid; i < 189 * 32; i += 256) {
        const int ict = i >> 5, oc = i & 31;
        const int oc96 = ocg * 32 + oc;
        wt[i] = (oc96 < 48) ? w1o[oc96 * 189 + ict] : w1g[(oc96 - 48) * 189 + ict];
    }
    if (tid < 32) {
        const int oc96 = ocg * 32 + tid;
        bs[tid] = (oc96 < 48) ? b1o[oc96] : b1g[oc96 - 48];
    }
    __syncthreads();

    const int og = tid >> 6;            // wave id -> oc octet (wave-uniform)
    const int q  = tid & 63;            // 16 rows x 4 quad-cols
    const int qy = q >> 2, qx4 = (q & 3) * 4;
    const int oc8 = og * 8;

    float acc[4][8];
    #pragma unroll
    for (int i = 0; i < 4; i++)
        #pragma unroll
        for (int j = 0; j < 8; j++) acc[i][j] = bs[oc8 + j];

    for (int ic = 0; ic < CIN; ic++) {
        #pragma unroll
        for (int ky = 0; ky < 3; ky++) {
            const float4 f0 = *(const float4*)&xs[ic * 360 + (qy + ky) * 20 + qx4];
            const float4 f1 = *(const float4*)&xs[ic * 360 + (qy + ky) * 20 + qx4 + 4];
            const float xw[8] = {f0.x, f0.y, f0.z, f0.w, f1.x, f1.y, f1.z, f1.w};
            #pragma unroll
            for (int kx = 0; kx < 3; kx++) {
                const float4 wa = *(const float4*)&wt[(ic * 9 + ky * 3 + kx) * 32 + oc8];
                const float4 wb = *(const float4*)&wt[(ic * 9 + ky * 3 + kx) * 32 + oc8 + 4];
                const float wj[8] = {wa.x, wa.y, wa.z, wa.w, wb.x, wb.y, wb.z, wb.w};
                #pragma unroll
                for (int i = 0; i < 4; i++)
                    #pragma unroll
                    for (int j = 0; j < 8; j++)
                        acc[i][j] = fmaf(xw[i + kx], wj[j], acc[i][j]);
            }
        }
    }

    const int oy = ty0 + qy;
    const int ox0 = tx0 + qx4;
    if (oy < H0) {
        #pragma unroll
        for (int j = 0; j < 8; j++) {
            const int oc96 = ocg * 32 + oc8 + j;    // wave-uniform
            float* base = (oc96 < 48)
                ? hid_o + ((size_t)b * HIDC + oc96) * NP
                : hid_g + ((size_t)b * HIDC + (oc96 - 48)) * NP;
            if (ox0 + 3 < H0) {
                *reinterpret_cast<float4*>(base + oy * H0 + ox0) =
                    make_float4(fmaxf(acc[0][j], 0.f), fmaxf(acc[1][j], 0.f),
                                fmaxf(acc[2][j], 0.f), fmaxf(acc[3][j], 0.f));
            } else {
                #pragma unroll
                for (int i = 0; i < 4; i++)
                    if (ox0 + i < H0) base[oy * H0 + ox0 + i] = fmaxf(acc[i][j], 0.f);
            }
        }
    }
}

// ---------------------------------------------------------------------------
// K2 v4 (unchanged): conv2 both heads + mask epilogue, MLP-first design.
// ---------------------------------------------------------------------------
__global__ __launch_bounds__(256) void k2_conv2_masks(
    const float* __restrict__ hid_o, const float* __restrict__ hid_g,
    const float* __restrict__ w2o, const float* __restrict__ b2o,
    const float* __restrict__ w2g, const float* __restrict__ b2g,
    float* __restrict__ v_out,
    float* __restrict__ g_buf, float* __restrict__ m_lp, float* __restrict__ m_hp)
{
    __shared__ __align__(16) float wo_s[HIDC * 9 * 8];  // [(ic*9+tap)*8 + d]
    __shared__ float wg_s[HIDC * 9];
    __shared__ float red[4][32][12];
    __shared__ float res_s[32][28];
    const int tid = threadIdx.x;
    const int b = blockIdx.y;

    for (int i = tid; i < HIDC * 9 * 8; i += 256) {
        const int d = i / (HIDC * 9), r = i - d * (HIDC * 9);
        wo_s[r * 8 + d] = w2o[i];
    }
    for (int i = tid; i < HIDC * 9; i += 256) wg_s[i] = w2g[i];
    __syncthreads();

    const int pxl = tid & 31;
    const int s   = tid >> 5;                // 0..7
    const int w   = tid >> 6;                // wave
    const int px  = blockIdx.x * 32 + pxl;
    const bool valid = (px < NP);
    const int oy = px / H0, ox = px - oy * H0;
    const int ic0 = s * 6;
    const float* po = hid_o + ((size_t)b * HIDC + ic0) * NP;
    const float* pg = hid_g + ((size_t)b * HIDC + ic0) * NP;

    float a[8] = {0.f, 0.f, 0.f, 0.f, 0.f, 0.f, 0.f, 0.f};
    float ag = 0.f;

    #pragma unroll 1
    for (int ky = 0; ky < 3; ky++) {
        const int iy = oy + ky - 1;
        const bool rok = valid && ((unsigned)iy < (unsigned)H0);
        #pragma unroll
        for (int kx = 0; kx < 3; kx++) {
            const int ix = ox + kx - 1;
            const bool ok = rok && ((unsigned)ix < (unsigned)H0);
            const int off = iy * H0 + ix;
            const int tap = ky * 3 + kx;
            #pragma unroll
            for (int j = 0; j < 6; j++) {
                const float vo = ok ? po[j * NP + off] : 0.f;
                const float vg = ok ? pg[j * NP + off] : 0.f;
                const int wb = ((ic0 + j) * 9 + tap) * 8;
                const float4 wA = *(const float4*)&wo_s[wb];
                const float4 wB = *(const float4*)&wo_s[wb + 4];
                a[0] = fmaf(vo, wA.x, a[0]); a[1] = fmaf(vo, wA.y, a[1]);
                a[2] = fmaf(vo, wA.z, a[2]); a[3] = fmaf(vo, wA.w, a[3]);
                a[4] = fmaf(vo, wB.x, a[4]); a[5] = fmaf(vo, wB.y, a[5]);
                a[6] = fmaf(vo, wB.z, a[6]); a[7] = fmaf(vo, wB.w, a[7]);
                ag = fmaf(vg, wg_s[(ic0 + j) * 9 + tap], ag);
            }
        }
    }

    #pragma unroll
    for (int n = 0; n < 8; n++) a[n] += __shfl_xor(a[n], 32);
    ag += __shfl_xor(ag, 32);
    if ((tid & 32) == 0) {
        #pragma unroll
        for (int n = 0; n < 8; n++) red[w][pxl][n] = a[n];
        red[w][pxl][8] = ag;
    }
    __syncthreads();

    if (tid < 32 && valid) {
        float v[8];
        #pragma unroll
        for (int n = 0; n < 8; n++)
            v[n] = tanh_fast(red[0][tid][n] + red[1][tid][n] + red[2][tid][n]
                             + red[3][tid][n] + b2o[n]);
        const float agf = red[0][tid][8] + red[1][tid][8] + red[2][tid][8]
                        + red[3][tid][8] + b2g[0];
        const float g = 1.f / (1.f + __expf(-agf));

        constexpr float DT[8][9] = {
            {-1, 0, 1, -1, 0, 1, -1, 0, 1},
            {-1,-1, 0, -1, 0, 1,  0, 1, 1},
            {-1,-1,-1,  0, 0, 0,  1, 1, 1},
            { 0,-1,-1,  1, 0,-1,  1, 1, 0},
            { 1, 0,-1,  1, 0,-1,  1, 0,-1},
            { 1, 1, 0,  1, 0,-1,  0,-1,-1},
            { 1, 1, 1,  0, 0, 0, -1,-1,-1},
            { 0, 1, 1, -1, 0, 1, -1,-1, 0}};
        float ker[9];
        #pragma unroll
        for (int n = 0; n < 9; n++) {
            float t = 0.f;
            #pragma unroll
            for (int d = 0; d < 8; d++) t += v[d] * DT[d][n];
            ker[n] = -0.125f * t;
        }
        ker[4] += 2.5f;
        float mx = ker[0];
        #pragma unroll
        for (int n = 1; n < 9; n++) mx = fmaxf(mx, ker[n]);
        float exn[9], sum = 0.f;
        #pragma unroll
        for (int n = 0; n < 9; n++) { exn[n] = __expf((ker[n] - mx) * 2.0f); sum += exn[n]; }
        const float rs = 1.f / sum;
        float mean = 0.f;
        #pragma unroll
        for (int n = 0; n < 9; n++) mean += ker[n];
        mean *= (1.f / 9.f);
        float den = 1e-8f;
        #pragma unroll
        for (int n = 0; n < 9; n++) den += fabsf(ker[n] - mean);
        const float rd = 1.f / den;

        #pragma unroll
        for (int n = 0; n < 8; n++) res_s[tid][n] = v[n];
        res_s[tid][8] = g;
        #pragma unroll
        for (int n = 0; n < 9; n++) {
            res_s[tid][9 + n]  = exn[n] * rs;
            res_s[tid][18 + n] = (ker[n] - mean) * rd;
        }
    }
    __syncthreads();

    const int px0 = blockIdx.x * 32;
    for (int j = tid; j < 27 * 32; j += 256) {
        const int plane = j >> 5, pl = j & 31;
        const int p = px0 + pl;
        if (p >= NP) continue;
        const float val = res_s[pl][plane];
        float* dst;
        if (plane < 8)        dst = v_out + ((size_t)b * 8 + plane) * NP;
        else if (plane == 8)  dst = g_buf + (size_t)b * NP;
        else if (plane < 18)  dst = m_lp + ((size_t)b * 9 + (plane - 9)) * NP;
        else                  dst = m_hp + ((size_t)b * 9 + (plane - 18)) * NP;
        dst[p] = val;
    }
}

// ---------------------------------------------------------------------------
// K4 v2 (k3 fused in): hi-res blend. One thread = one float4 of an output
// row. The low-res px (h0r, wq) is constant within the float4, so the thread
// loads the 3x3 reflect patch + 18 masks ONCE, computes alp/ahp in registers
// (the old k3), and reuses the patch for bilinear (y0,x0 always fall inside
// the patch window - proved: y0 in {h0r-1,h0r} clamped in-bounds).
// blockIdx.y==CIN writes g_up.
// ---------------------------------------------------------------------------
__global__ __launch_bounds__(256) void k4_up(
    const float* __restrict__ x, const float* __restrict__ g_buf,
    const float* __restrict__ m_lp, const float* __restrict__ m_hp,
    const float* __restrict__ beta,
    float* __restrict__ y_out, float* __restrict__ gup_out)
{
    const int tid = threadIdx.x;
    if (tid >= 243) return;
    const int c = blockIdx.y;              // 0..20 = channel, 21 = g_up
    const int b = blockIdx.z;
    const int H = blockIdx.x * 3 + tid / 81;
    const int wq = tid % 81;
    const int h0r = H >> 2;
    const int lpx = h0r * H0 + wq;
    const float g = g_buf[(size_t)b * NP + lpx];
    if (c == CIN) {
        *reinterpret_cast<float4*>(gup_out + (size_t)b * NPH + H * HH + wq * 4) =
            make_float4(g, g, g, g);
        return;
    }
    // masks (shared across the 4x4 up-block -> scalar per thread)
    float ml[9], mh[9];
    const float* mlb = m_lp + (size_t)b * 9 * NP + lpx;
    const float* mhb = m_hp + (size_t)b * 9 * NP + lpx;
    #pragma unroll
    for (int n = 0; n < 9; n++) { ml[n] = mlb[n * NP]; mh[n] = mhb[n * NP]; }
    // 3x3 reflect patch of channel c
    const float* xc = x + ((size_t)b * CIN + c) * NP;
    float p[3][3];
    #pragma unroll
    for (int ky = 0; ky < 3; ky++) {
        int iy = h0r + ky - 1;
        iy = iy < 0 ? -iy : (iy > H0 - 1 ? 2 * (H0 - 1) - iy : iy);
        #pragma unroll
        for (int kx = 0; kx < 3; kx++) {
            int ix = wq + kx - 1;
            ix = ix < 0 ? -ix : (ix > H0 - 1 ? 2 * (H0 - 1) - ix : ix);
            p[ky][kx] = xc[iy * H0 + ix];
        }
    }
    // low-res 9-tap aggregates (old k3)
    float alp = 0.f, ahp = 0.f;
    #pragma unroll
    for (int ky = 0; ky < 3; ky++)
        #pragma unroll
        for (int kx = 0; kx < 3; kx++) {
            alp = fmaf(p[ky][kx], ml[ky * 3 + kx], alp);
            ahp = fmaf(p[ky][kx], mh[ky * 3 + kx], ahp);
        }
    const float tb = tanh_fast(beta[0]);
    const float lam = 0.15f * (1.f - g);
    const float gh = tb * g;
    // bilinear from patch registers
    const float ysf = (float)H * (80.f / 323.f);
    int y0 = (int)ysf;
    if (y0 > H0 - 2) y0 = H0 - 2;
    const float wy = ysf - (float)y0;
    const int sy = y0 - h0r + 1;           // 0 or 1
    float res[4];
    #pragma unroll
    for (int i = 0; i < 4; i++) {
        const int W = wq * 4 + i;
        const float xsf = (float)W * (80.f / 323.f);
        int x0 = (int)xsf;
        if (x0 > H0 - 2) x0 = H0 - 2;
        const float wx = xsf - (float)x0;
        const int sx = x0 - wq + 1;        // 0 or 1
        const float x00 = sy == 0 ? (sx == 0 ? p[0][0] : p[0][1]) : (sx == 0 ? p[1][0] : p[1][1]);
        const float x01 = sy == 0 ? (sx == 0 ? p[0][1] : p[0][2]) : (sx == 0 ? p[1][1] : p[1][2]);
        const float x10 = sy == 0 ? (sx == 0 ? p[1][0] : p[1][1]) : (sx == 0 ? p[2][0] : p[2][1]);
        const float x11 = sy == 0 ? (sx == 0 ? p[1][1] : p[1][2]) : (sx == 0 ? p[2][1] : p[2][2]);
        const float top = x00 + (x01 - x00) * wx;
        const float bot = x10 + (x11 - x10) * wx;
        const float xup = top + (bot - top) * wy;
        res[i] = xup + lam * (alp - xup) + gh * ahp;
    }
    *reinterpret_cast<float4*>(y_out + ((size_t)b * CIN + c) * NPH + H * HH + wq * 4) =
        make_float4(res[0], res[1], res[2], res[3]);
}

// ---------------------------------------------------------------------------
extern "C" void kernel_launch(void* const* d_in, const int* in_sizes, int n_in,
                              void* d_out, int out_size, void* d_ws, size_t ws_size,
                              hipStream_t stream)
{
    const float* x    = (const float*)d_in[0];
    const float* w1o  = (const float*)d_in[1];
    const float* b1o  = (const float*)d_in[2];
    const float* w2o  = (const float*)d_in[3];
    const float* b2o  = (const float*)d_in[4];
    const float* w1g  = (const float*)d_in[5];
    const float* b1g  = (const float*)d_in[6];
    const float* w2g  = (const float*)d_in[7];
    const float* b2g  = (const float*)d_in[8];
    const float* beta = (const float*)d_in[9];
    float* out = (float*)d_out;
    float* wsf = (float*)d_ws;

    float* hid_o = wsf;
    float* hid_g = hid_o + (size_t)B_N * HIDC * NP;
    float* m_lp  = hid_g + (size_t)B_N * HIDC * NP;
    float* m_hp  = m_lp + (size_t)B_N * 9 * NP;
    float* g_buf = m_hp + (size_t)B_N * 9 * NP;

    // output layout: y [4,21,324,324], v [4,8,81,81], g_up [4,1,324,324]
    float* y_out = out;
    float* v_out = out + (size_t)B_N * CIN * NPH;
    float* gup   = v_out + (size_t)B_N * 8 * NP;

    k1_conv1<<<dim3(36, 3, B_N), 256, 0, stream>>>(x, w1o, b1o, w1g, b1g, hid_o, hid_g);
    k2_conv2_masks<<<dim3((NP + 31) / 32, B_N), 256, 0, stream>>>(
        hid_o, hid_g, w2o, b2o, w2g, b2g, v_out, g_buf, m_lp, m_hp);
    k4_up<<<dim3(108, CIN + 1, B_N), 256, 0, stream>>>(x, g_buf, m_lp, m_hp, beta, y_out, gup);
}

// Round 6
// 153.336 us; speedup vs baseline: 1.5723x; 1.0032x over previous
//
#include <hip/hip_runtime.h>
#include <math.h>

// Problem constants
#define B_N   4
#define CIN   21
#define HIDC  48
#define H0    81
#define NP    6561      // 81*81
#define HH    324
#define NPH   104976    // 324*324

__device__ __forceinline__ float tanh_fast(float x) {
    float e = __expf(2.f * x);
    return 1.f - 2.f / (e + 1.f);
}

// ---------------------------------------------------------------------------
// K1 v6: conv1 both heads (21 -> 96 = 48 o + 48 g), relu. MLP-first layout:
// block = 256 consecutive pixels, blockIdx.y = 12-oc group (8 groups of 12).
// x reads straight from L1/L2 (fully coalesced, no LDS staging, no barrier
// in the hot path, no bank conflicts); weights 9.1 KB in LDS, read as
// wave-uniform float4 broadcasts. 832 blocks, FMA-bound (~6 us floor).
// ---------------------------------------------------------------------------
__global__ __launch_bounds__(256) void k1_conv1(
    const float* __restrict__ x,
    const float* __restrict__ w1o, const float* __restrict__ b1o,
    const float* __restrict__ w1g, const float* __restrict__ b1g,
    float* __restrict__ hid_o, float* __restrict__ hid_g)
{
    __shared__ __align__(16) float wt[189 * 12];  // [ict*12 + oc]
    __shared__ float bs[12];
    const int tid = threadIdx.x;
    const int grp = blockIdx.y;          // 0..7 ; 0..3 -> head_o, 4..7 -> head_g
    const int b   = blockIdx.z;
    const bool head_o = (grp < 4);
    const int ocb = (grp & 3) * 12;      // oc base within the head
    const float* wsrc = head_o ? w1o : w1g;
    for (int i = tid; i < 189 * 12; i += 256) {
        const int ict = i / 12, oc = i - ict * 12;
        wt[i] = wsrc[(ocb + oc) * 189 + ict];
    }
    if (tid < 12) bs[tid] = (head_o ? b1o : b1g)[ocb + tid];
    __syncthreads();

    const int px = blockIdx.x * 256 + tid;
    const bool valid = (px < NP);
    const int oy = px / H0, ox = px - oy * H0;
    const float* xb = x + (size_t)b * CIN * NP;

    float acc[12];
    #pragma unroll
    for (int j = 0; j < 12; j++) acc[j] = bs[j];

    for (int ic = 0; ic < CIN; ic++) {
        const float* xc = xb + ic * NP;
        float xv[9];
        #pragma unroll
        for (int ky = 0; ky < 3; ky++) {
            const int iy = oy + ky - 1;
            const bool rok = valid && ((unsigned)iy < (unsigned)H0);
            #pragma unroll
            for (int kx = 0; kx < 3; kx++) {
                const int ix = ox + kx - 1;
                const bool ok = rok && ((unsigned)ix < (unsigned)H0);
                xv[ky * 3 + kx] = ok ? xc[iy * H0 + ix] : 0.f;
            }
        }
        #pragma unroll
        for (int tap = 0; tap < 9; tap++) {
            const float4 w0 = *(const float4*)&wt[(ic * 9 + tap) * 12];
            const float4 w1 = *(const float4*)&wt[(ic * 9 + tap) * 12 + 4];
            const float4 w2 = *(const float4*)&wt[(ic * 9 + tap) * 12 + 8];
            const float wj[12] = {w0.x, w0.y, w0.z, w0.w, w1.x, w1.y, w1.z, w1.w,
                                  w2.x, w2.y, w2.z, w2.w};
            const float xvt = xv[tap];
            #pragma unroll
            for (int j = 0; j < 12; j++) acc[j] = fmaf(xvt, wj[j], acc[j]);
        }
    }

    if (valid) {
        float* outp = (head_o ? hid_o : hid_g) + ((size_t)b * HIDC + ocb) * NP + px;
        #pragma unroll
        for (int j = 0; j < 12; j++) outp[j * NP] = fmaxf(acc[j], 0.f);
    }
}

// ---------------------------------------------------------------------------
// K2 v4 (unchanged): conv2 both heads + mask epilogue, MLP-first design.
// ---------------------------------------------------------------------------
__global__ __launch_bounds__(256) void k2_conv2_masks(
    const float* __restrict__ hid_o, const float* __restrict__ hid_g,
    const float* __restrict__ w2o, const float* __restrict__ b2o,
    const float* __restrict__ w2g, const float* __restrict__ b2g,
    float* __restrict__ v_out,
    float* __restrict__ g_buf, float* __restrict__ m_lp, float* __restrict__ m_hp)
{
    __shared__ __align__(16) float wo_s[HIDC * 9 * 8];  // [(ic*9+tap)*8 + d]
    __shared__ float wg_s[HIDC * 9];
    __shared__ float red[4][32][12];
    __shared__ float res_s[32][28];
    const int tid = threadIdx.x;
    const int b = blockIdx.y;

    for (int i = tid; i < HIDC * 9 * 8; i += 256) {
        const int d = i / (HIDC * 9), r = i - d * (HIDC * 9);
        wo_s[r * 8 + d] = w2o[i];
    }
    for (int i = tid; i < HIDC * 9; i += 256) wg_s[i] = w2g[i];
    __syncthreads();

    const int pxl = tid & 31;
    const int s   = tid >> 5;                // 0..7
    const int w   = tid >> 6;                // wave
    const int px  = blockIdx.x * 32 + pxl;
    const bool valid = (px < NP);
    const int oy = px / H0, ox = px - oy * H0;
    const int ic0 = s * 6;
    const float* po = hid_o + ((size_t)b * HIDC + ic0) * NP;
    const float* pg = hid_g + ((size_t)b * HIDC + ic0) * NP;

    float a[8] = {0.f, 0.f, 0.f, 0.f, 0.f, 0.f, 0.f, 0.f};
    float ag = 0.f;

    #pragma unroll 1
    for (int ky = 0; ky < 3; ky++) {
        const int iy = oy + ky - 1;
        const bool rok = valid && ((unsigned)iy < (unsigned)H0);
        #pragma unroll
        for (int kx = 0; kx < 3; kx++) {
            const int ix = ox + kx - 1;
            const bool ok = rok && ((unsigned)ix < (unsigned)H0);
            const int off = iy * H0 + ix;
            const int tap = ky * 3 + kx;
            #pragma unroll
            for (int j = 0; j < 6; j++) {
                const float vo = ok ? po[j * NP + off] : 0.f;
                const float vg = ok ? pg[j * NP + off] : 0.f;
                const int wb = ((ic0 + j) * 9 + tap) * 8;
                const float4 wA = *(const float4*)&wo_s[wb];
                const float4 wB = *(const float4*)&wo_s[wb + 4];
                a[0] = fmaf(vo, wA.x, a[0]); a[1] = fmaf(vo, wA.y, a[1]);
                a[2] = fmaf(vo, wA.z, a[2]); a[3] = fmaf(vo, wA.w, a[3]);
                a[4] = fmaf(vo, wB.x, a[4]); a[5] = fmaf(vo, wB.y, a[5]);
                a[6] = fmaf(vo, wB.z, a[6]); a[7] = fmaf(vo, wB.w, a[7]);
                ag = fmaf(vg, wg_s[(ic0 + j) * 9 + tap], ag);
            }
        }
    }

    #pragma unroll
    for (int n = 0; n < 8; n++) a[n] += __shfl_xor(a[n], 32);
    ag += __shfl_xor(ag, 32);
    if ((tid & 32) == 0) {
        #pragma unroll
        for (int n = 0; n < 8; n++) red[w][pxl][n] = a[n];
        red[w][pxl][8] = ag;
    }
    __syncthreads();

    if (tid < 32 && valid) {
        float v[8];
        #pragma unroll
        for (int n = 0; n < 8; n++)
            v[n] = tanh_fast(red[0][tid][n] + red[1][tid][n] + red[2][tid][n]
                             + red[3][tid][n] + b2o[n]);
        const float agf = red[0][tid][8] + red[1][tid][8] + red[2][tid][8]
                        + red[3][tid][8] + b2g[0];
        const float g = 1.f / (1.f + __expf(-agf));

        constexpr float DT[8][9] = {
            {-1, 0, 1, -1, 0, 1, -1, 0, 1},
            {-1,-1, 0, -1, 0, 1,  0, 1, 1},
            {-1,-1,-1,  0, 0, 0,  1, 1, 1},
            { 0,-1,-1,  1, 0,-1,  1, 1, 0},
            { 1, 0,-1,  1, 0,-1,  1, 0,-1},
            { 1, 1, 0,  1, 0,-1,  0,-1,-1},
            { 1, 1, 1,  0, 0, 0, -1,-1,-1},
            { 0, 1, 1, -1, 0, 1, -1,-1, 0}};
        float ker[9];
        #pragma unroll
        for (int n = 0; n < 9; n++) {
            float t = 0.f;
            #pragma unroll
            for (int d = 0; d < 8; d++) t += v[d] * DT[d][n];
            ker[n] = -0.125f * t;
        }
        ker[4] += 2.5f;
        float mx = ker[0];
        #pragma unroll
        for (int n = 1; n < 9; n++) mx = fmaxf(mx, ker[n]);
        float exn[9], sum = 0.f;
        #pragma unroll
        for (int n = 0; n < 9; n++) { exn[n] = __expf((ker[n] - mx) * 2.0f); sum += exn[n]; }
        const float rs = 1.f / sum;
        float mean = 0.f;
        #pragma unroll
        for (int n = 0; n < 9; n++) mean += ker[n];
        mean *= (1.f / 9.f);
        float den = 1e-8f;
        #pragma unroll
        for (int n = 0; n < 9; n++) den += fabsf(ker[n] - mean);
        const float rd = 1.f / den;

        #pragma unroll
        for (int n = 0; n < 8; n++) res_s[tid][n] = v[n];
        res_s[tid][8] = g;
        #pragma unroll
        for (int n = 0; n < 9; n++) {
            res_s[tid][9 + n]  = exn[n] * rs;
            res_s[tid][18 + n] = (ker[n] - mean) * rd;
        }
    }
    __syncthreads();

    const int px0 = blockIdx.x * 32;
    for (int j = tid; j < 27 * 32; j += 256) {
        const int plane = j >> 5, pl = j & 31;
        const int p = px0 + pl;
        if (p >= NP) continue;
        const float val = res_s[pl][plane];
        float* dst;
        if (plane < 8)        dst = v_out + ((size_t)b * 8 + plane) * NP;
        else if (plane == 8)  dst = g_buf + (size_t)b * NP;
        else if (plane < 18)  dst = m_lp + ((size_t)b * 9 + (plane - 9)) * NP;
        else                  dst = m_hp + ((size_t)b * 9 + (plane - 18)) * NP;
        dst[p] = val;
    }
}

// ---------------------------------------------------------------------------
// K4 v3: hi-res blend, low-res-row-centric. Block = (low-res row h0r, half
// of the channel planes, b). Stage masks/g (6 KB) + 3 x-rows (11 KB) ONCE,
// phase A computes per-(c,wq) aggregates into LDS, phase B emits 4 hi-res
// rows x 11 planes (float4/thread, coalesced). Kills the 22x mask re-fetch
// of the previous per-channel grid (~250 MB -> ~15 MB of cache traffic).
// ---------------------------------------------------------------------------
__global__ __launch_bounds__(256) void k4_up(
    const float* __restrict__ x, const float* __restrict__ g_buf,
    const float* __restrict__ m_lp, const float* __restrict__ m_hp,
    const float* __restrict__ beta,
    float* __restrict__ y_out, float* __restrict__ gup_out)
{
    __shared__ float ml_s[9][81];
    __shared__ float mh_s[9][81];
    __shared__ float g_s[81];
    __shared__ float xrow[3][11][84];
    __shared__ float alp_s[11][84];
    __shared__ float ahp_s[11][84];
    const int tid  = threadIdx.x;
    const int h0r  = blockIdx.x;         // 0..80
    const int ygrp = blockIdx.y;         // 0..1
    const int b    = blockIdx.z;
    const int c0   = ygrp * 11;          // channels c0..c0+nc-1
    const int nc   = (ygrp == 0) ? 11 : 10;

    // stage masks + gate for this low-res row
    const int rb = h0r * H0;
    for (int i = tid; i < 19 * 81; i += 256) {
        const int pl = i / 81, wq = i - pl * 81;
        if (pl < 9)       ml_s[pl][wq] = m_lp[((size_t)b * 9 + pl) * NP + rb + wq];
        else if (pl < 18) mh_s[pl - 9][wq] = m_hp[((size_t)b * 9 + (pl - 9)) * NP + rb + wq];
        else              g_s[wq] = g_buf[(size_t)b * NP + rb + wq];
    }
    // stage the 3 (reflected) x rows for my channels
    const int r0 = (h0r == 0) ? 1 : h0r - 1;
    const int r2 = (h0r == H0 - 1) ? H0 - 2 : h0r + 1;
    const int rr[3] = {r0, h0r, r2};
    for (int i = tid; i < 3 * nc * 81; i += 256) {
        const int t = i / (nc * 81), rem = i - t * nc * 81;
        const int cc = rem / 81, wq = rem - cc * 81;
        xrow[t][cc][wq] = x[((size_t)b * CIN + c0 + cc) * NP + rr[t] * H0 + wq];
    }
    __syncthreads();

    // phase A: per-(c,wq) low-res aggregates
    for (int i = tid; i < nc * 81; i += 256) {
        const int cc = i / 81, wq = i - cc * 81;
        const int xm = (wq == 0) ? 1 : wq - 1;
        const int xp = (wq == H0 - 1) ? H0 - 2 : wq + 1;
        float alp = 0.f, ahp = 0.f;
        #pragma unroll
        for (int t = 0; t < 3; t++) {
            const float p0 = xrow[t][cc][xm];
            const float p1 = xrow[t][cc][wq];
            const float p2 = xrow[t][cc][xp];
            alp += p0 * ml_s[t * 3 + 0][wq] + p1 * ml_s[t * 3 + 1][wq] + p2 * ml_s[t * 3 + 2][wq];
            ahp += p0 * mh_s[t * 3 + 0][wq] + p1 * mh_s[t * 3 + 1][wq] + p2 * mh_s[t * 3 + 2][wq];
        }
        alp_s[cc][wq] = alp;
        ahp_s[cc][wq] = ahp;
    }
    __syncthreads();

    const float tb = tanh_fast(beta[0]);
    // phase B: 11 planes x 4 hi-res rows x 81 float4s
    for (int i = tid; i < 11 * 4 * 81; i += 256) {
        const int pl = i / 324, rem = i - pl * 324;
        const int dh = rem / 81, wq = rem - dh * 81;
        const int H = h0r * 4 + dh;
        if (ygrp == 1 && pl == 10) {
            const float g = g_s[wq];
            *reinterpret_cast<float4*>(gup_out + (size_t)b * NPH + H * HH + wq * 4) =
                make_float4(g, g, g, g);
            continue;
        }
        const int cc = pl;
        const int c = c0 + pl;
        const float g = g_s[wq];
        const float lam = 0.15f * (1.f - g);
        const float gh = tb * g;
        const float alp = alp_s[cc][wq];
        const float ahp = ahp_s[cc][wq];
        // bilinear from staged rows
        const float ysf = (float)H * (80.f / 323.f);
        int y0 = (int)ysf;
        if (y0 > H0 - 2) y0 = H0 - 2;
        const float wy = ysf - (float)y0;
        const int sy = y0 - h0r + 1;    // 0 or 1 (proved in range)
        const int xm = (wq == 0) ? 1 : wq - 1;   // staged col for wq-1 (never used when wq==0)
        const int xp = (wq == H0 - 1) ? H0 - 2 : wq + 1;  // never used when wq==80
        const float a0 = xrow[sy][cc][(wq == 0) ? 0 : xm];
        const float a1 = xrow[sy][cc][wq];
        const float a2 = xrow[sy][cc][(wq == H0 - 1) ? H0 - 1 : xp];
        const float b0 = xrow[sy + 1][cc][(wq == 0) ? 0 : xm];
        const float b1 = xrow[sy + 1][cc][wq];
        const float b2 = xrow[sy + 1][cc][(wq == H0 - 1) ? H0 - 1 : xp];
        float res[4];
        #pragma unroll
        for (int k = 0; k < 4; k++) {
            const int W = wq * 4 + k;
            const float xsf = (float)W * (80.f / 323.f);
            int x0 = (int)xsf;
            if (x0 > H0 - 2) x0 = H0 - 2;
            const float wx = xsf - (float)x0;
            const int sx = x0 - wq + 1;   // 0 or 1
            const float top = (sx == 0) ? a0 + (a1 - a0) * wx : a1 + (a2 - a1) * wx;
            const float bot = (sx == 0) ? b0 + (b1 - b0) * wx : b1 + (b2 - b1) * wx;
            const float xup = top + (bot - top) * wy;
            res[k] = xup + lam * (alp - xup) + gh * ahp;
        }
        *reinterpret_cast<float4*>(y_out + ((size_t)b * CIN + c) * NPH + H * HH + wq * 4) =
            make_float4(res[0], res[1], res[2], res[3]);
    }
}

// ---------------------------------------------------------------------------
extern "C" void kernel_launch(void* const* d_in, const int* in_sizes, int n_in,
                              void* d_out, int out_size, void* d_ws, size_t ws_size,
                              hipStream_t stream)
{
    const float* x    = (const float*)d_in[0];
    const float* w1o  = (const float*)d_in[1];
    const float* b1o  = (const float*)d_in[2];
    const float* w2o  = (const float*)d_in[3];
    const float* b2o  = (const float*)d_in[4];
    const float* w1g  = (const float*)d_in[5];
    const float* b1g  = (const float*)d_in[6];
    const float* w2g  = (const float*)d_in[7];
    const float* b2g  = (const float*)d_in[8];
    const float* beta = (const float*)d_in[9];
    float* out = (float*)d_out;
    float* wsf = (float*)d_ws;

    float* hid_o = wsf;
    float* hid_g = hid_o + (size_t)B_N * HIDC * NP;
    float* m_lp  = hid_g + (size_t)B_N * HIDC * NP;
    float* m_hp  = m_lp + (size_t)B_N * 9 * NP;
    float* g_buf = m_hp + (size_t)B_N * 9 * NP;

    // output layout: y [4,21,324,324], v [4,8,81,81], g_up [4,1,324,324]
    float* y_out = out;
    float* v_out = out + (size_t)B_N * CIN * NPH;
    float* gup   = v_out + (size_t)B_N * 8 * NP;

    k1_conv1<<<dim3((NP + 255) / 256, 8, B_N), 256, 0, stream>>>(
        x, w1o, b1o, w1g, b1g, hid_o, hid_g);
    k2_conv2_masks<<<dim3((NP + 31) / 32, B_N), 256, 0, stream>>>(
        hid_o, hid_g, w2o, b2o, w2g, b2g, v_out, g_buf, m_lp, m_hp);
    k4_up<<<dim3(H0, 2, B_N), 256, 0, stream>>>(x, g_buf, m_lp, m_hp, beta, y_out, gup);
}